// Round 1
// baseline (4206.361 us; speedup 1.0000x reference)
//
#include <hip/hip_runtime.h>
#include <hip/hip_bf16.h>

// Problem constants (fixed by setup_inputs)
#define D     128
#define NLIT  32000
#define NCLA  64000
#define KLIT  3
#define NEDGE 192000
#define BGR   32
#define ITERS 4
#define LITS_PER_GRAPH 1000

__device__ __forceinline__ float sigf(float x) { return 1.f / (1.f + __expf(-x)); }

// ---------------------------------------------------------------------------
// init h_c = C_w + C_b broadcast over NCLA rows
// ---------------------------------------------------------------------------
__global__ void init_hc_kernel(float* __restrict__ h_c,
                               const float* __restrict__ C_w,
                               const float* __restrict__ C_b) {
    int idx = blockIdx.x * blockDim.x + threadIdx.x;
    if (idx < NCLA * D) {
        int d = idx & (D - 1);
        h_c[idx] = C_w[d] + C_b[d];
    }
}

// ---------------------------------------------------------------------------
// CSR build: counts -> scan -> fill
// ---------------------------------------------------------------------------
__global__ void count_edges_kernel(const int* __restrict__ lit_idx,
                                   int* __restrict__ counts) {
    int e = blockIdx.x * blockDim.x + threadIdx.x;
    if (e < NEDGE) atomicAdd(&counts[lit_idx[e]], 1);
}

// single block, 1024 threads, chunk of 32 each (covers 32768 >= NLIT)
__global__ void scan_kernel(const int* __restrict__ counts,
                            int* __restrict__ starts,
                            int* __restrict__ cursor) {
    __shared__ int ssum[1024];
    int t = threadIdx.x;
    int base = t * 32;
    int s = 0;
    for (int i = 0; i < 32; ++i) {
        int idx = base + i;
        if (idx < NLIT) s += counts[idx];
    }
    ssum[t] = s;
    __syncthreads();
    for (int off = 1; off < 1024; off <<= 1) {
        int v = (t >= off) ? ssum[t - off] : 0;
        __syncthreads();
        ssum[t] += v;
        __syncthreads();
    }
    int run = (t == 0) ? 0 : ssum[t - 1];   // exclusive prefix
    for (int i = 0; i < 32; ++i) {
        int idx = base + i;
        if (idx < NLIT) {
            starts[idx] = run;
            cursor[idx] = run;
            run += counts[idx];
        }
    }
    if (t == 1023) starts[NLIT] = run;      // == NEDGE
}

__global__ void fill_csr_kernel(const int* __restrict__ lit_idx,
                                const int* __restrict__ clause_idx,
                                int* __restrict__ cursor,
                                int* __restrict__ edge_clause) {
    int e = blockIdx.x * blockDim.x + threadIdx.x;
    if (e < NEDGE) {
        int l = lit_idx[e];
        int pos = atomicAdd(&cursor[l], 1);
        edge_clause[pos] = clause_idx[e];
    }
}

// ---------------------------------------------------------------------------
// msg_l[l][d] = sum over edges of literal l of h_c[clause][d]
// ---------------------------------------------------------------------------
__global__ void gather_msg_l_kernel(const float* __restrict__ h_c,
                                    float* __restrict__ msg_l,
                                    const int* __restrict__ starts,
                                    const int* __restrict__ edge_clause) {
    int idx = blockIdx.x * blockDim.x + threadIdx.x;
    if (idx >= NLIT * D) return;
    int l = idx >> 7;
    int d = idx & (D - 1);
    int s = starts[l], e = starts[l + 1];
    float acc = 0.f;
    for (int j = s; j < e; ++j) acc += h_c[edge_clause[j] * D + d];
    msg_l[idx] = acc;
}

// ---------------------------------------------------------------------------
// Clause LSTM, fused gather + GEMM (K=256) + pointwise.
// 64 rows/block, 512 threads, BN=512 (all gates), 8x8 register tile/thread.
// Thread tn owns cols {tn+64*jj} -> full i,f,g,o quadruples for d=tn, tn+64.
// ---------------------------------------------------------------------------
#define WPAD 516   // LDS row stride for W tile [k][n]
#define APAD 68    // LDS row stride for A tile [k][m]

__global__ __launch_bounds__(512, 2)
void clause_lstm_kernel(const float* __restrict__ h_l,       // NLIT x D (iteration-start)
                        float* __restrict__ h_c,             // NCLA x D in/out
                        float* __restrict__ c_c,             // NCLA x D in/out
                        const float* __restrict__ Wih,       // 512 x 128
                        const float* __restrict__ Whh,       // 512 x 128
                        const float* __restrict__ bih,       // 512
                        const float* __restrict__ bhh,       // 512
                        const int* __restrict__ lit_idx) {   // NEDGE
    __shared__ float Wl[16 * WPAD];
    __shared__ float Al[16 * APAD];
    __shared__ int   lidx[64 * 3];

    const int tid  = threadIdx.x;
    const int row0 = blockIdx.x * 64;
    const int tn   = tid & 63;
    const int tm   = tid >> 6;

    if (tid < 192) lidx[tid] = lit_idx[row0 * 3 + tid];

    float acc[8][8];
#pragma unroll
    for (int r = 0; r < 8; ++r)
#pragma unroll
        for (int j = 0; j < 8; ++j) acc[r][j] = 0.f;

    for (int k0 = 0; k0 < 256; k0 += 16) {
        __syncthreads();
        // stage W tile: 512 x 16
        {
            const float* Wsrc = (k0 < 128) ? Wih : Whh;
            const int kk0 = k0 & 127;
#pragma unroll
            for (int i = 0; i < 16; ++i) {
                int elem = tid + 512 * i;
                int n = elem >> 4;
                int k = elem & 15;
                Wl[k * WPAD + n] = Wsrc[n * 128 + kk0 + k];
            }
        }
        // stage A tile: 64 x 16 (k<128: fused 3-literal gather-sum; else h_c own rows)
#pragma unroll
        for (int i = 0; i < 2; ++i) {
            int elem = tid + 512 * i;
            int m = elem >> 4;
            int k = elem & 15;
            float v;
            if (k0 < 128) {
                int kk = k0 + k;
                v = h_l[lidx[m * 3 + 0] * D + kk]
                  + h_l[lidx[m * 3 + 1] * D + kk]
                  + h_l[lidx[m * 3 + 2] * D + kk];
            } else {
                v = h_c[(row0 + m) * D + (k0 - 128 + k)];
            }
            Al[k * APAD + m] = v;
        }
        __syncthreads();
#pragma unroll
        for (int k = 0; k < 16; ++k) {
            const float4* ap = (const float4*)&Al[k * APAD + tm * 8];
            float4 a0 = ap[0], a1 = ap[1];
            float a[8] = {a0.x, a0.y, a0.z, a0.w, a1.x, a1.y, a1.z, a1.w};
            float w[8];
#pragma unroll
            for (int j = 0; j < 8; ++j) w[j] = Wl[k * WPAD + tn + 64 * j];
#pragma unroll
            for (int r = 0; r < 8; ++r)
#pragma unroll
                for (int j = 0; j < 8; ++j) acc[r][j] += a[r] * w[j];
        }
    }

    // fused LSTM pointwise epilogue (gates in registers)
#pragma unroll
    for (int r = 0; r < 8; ++r) {
        int m = row0 + tm * 8 + r;
#pragma unroll
        for (int half = 0; half < 2; ++half) {
            int d = tn + 64 * half;
            float gi = acc[r][0 + half] + bih[d]       + bhh[d];
            float gf = acc[r][2 + half] + bih[128 + d] + bhh[128 + d];
            float gg = acc[r][4 + half] + bih[256 + d] + bhh[256 + d];
            float go = acc[r][6 + half] + bih[384 + d] + bhh[384 + d];
            float c_old = c_c[m * D + d];
            float c_new = sigf(gf) * c_old + sigf(gi) * tanhf(gg);
            float h_new = sigf(go) * tanhf(c_new);
            c_c[m * D + d] = c_new;
            h_c[m * D + d] = h_new;
        }
    }
}

// ---------------------------------------------------------------------------
// Literal LSTM: A = [msg_l | h_l_old[flip] | h_l_old], K=384, N=512
// ---------------------------------------------------------------------------
__global__ __launch_bounds__(512, 2)
void literal_lstm_kernel(const float* __restrict__ h_l_old,   // NLIT x D
                         const float* __restrict__ msg_l,     // NLIT x D
                         float* __restrict__ h_l_new,         // NLIT x D
                         float* __restrict__ c_l,             // NLIT x D in/out
                         const float* __restrict__ Wih,       // 512 x 256
                         const float* __restrict__ Whh,       // 512 x 128
                         const float* __restrict__ bih,
                         const float* __restrict__ bhh,
                         const int* __restrict__ flip_perm) {
    __shared__ float Wl[16 * WPAD];
    __shared__ float Al[16 * APAD];
    __shared__ int   flip[64];

    const int tid  = threadIdx.x;
    const int row0 = blockIdx.x * 64;
    const int tn   = tid & 63;
    const int tm   = tid >> 6;

    if (tid < 64) flip[tid] = flip_perm[row0 + tid];

    float acc[8][8];
#pragma unroll
    for (int r = 0; r < 8; ++r)
#pragma unroll
        for (int j = 0; j < 8; ++j) acc[r][j] = 0.f;

    for (int k0 = 0; k0 < 384; k0 += 16) {
        __syncthreads();
        // stage W tile
        {
#pragma unroll
            for (int i = 0; i < 16; ++i) {
                int elem = tid + 512 * i;
                int n = elem >> 4;
                int k = elem & 15;
                float v;
                if (k0 < 256) v = Wih[n * 256 + k0 + k];
                else          v = Whh[n * 128 + (k0 - 256) + k];
                Wl[k * WPAD + n] = v;
            }
        }
        // stage A tile
#pragma unroll
        for (int i = 0; i < 2; ++i) {
            int elem = tid + 512 * i;
            int m = elem >> 4;
            int k = elem & 15;
            float v;
            if (k0 < 128)      v = msg_l[(row0 + m) * D + k0 + k];
            else if (k0 < 256) v = h_l_old[flip[m] * D + (k0 - 128) + k];
            else               v = h_l_old[(row0 + m) * D + (k0 - 256) + k];
            Al[k * APAD + m] = v;
        }
        __syncthreads();
#pragma unroll
        for (int k = 0; k < 16; ++k) {
            const float4* ap = (const float4*)&Al[k * APAD + tm * 8];
            float4 a0 = ap[0], a1 = ap[1];
            float a[8] = {a0.x, a0.y, a0.z, a0.w, a1.x, a1.y, a1.z, a1.w};
            float w[8];
#pragma unroll
            for (int j = 0; j < 8; ++j) w[j] = Wl[k * WPAD + tn + 64 * j];
#pragma unroll
            for (int r = 0; r < 8; ++r)
#pragma unroll
                for (int j = 0; j < 8; ++j) acc[r][j] += a[r] * w[j];
        }
    }

#pragma unroll
    for (int r = 0; r < 8; ++r) {
        int m = row0 + tm * 8 + r;
#pragma unroll
        for (int half = 0; half < 2; ++half) {
            int d = tn + 64 * half;
            float gi = acc[r][0 + half] + bih[d]       + bhh[d];
            float gf = acc[r][2 + half] + bih[128 + d] + bhh[128 + d];
            float gg = acc[r][4 + half] + bih[256 + d] + bhh[256 + d];
            float go = acc[r][6 + half] + bih[384 + d] + bhh[384 + d];
            float c_old = c_l[m * D + d];
            float c_new = sigf(gf) * c_old + sigf(gi) * tanhf(gg);
            float h_new = sigf(go) * tanhf(c_new);
            c_l[m * D + d]    = c_new;
            h_l_new[m * D + d] = h_new;
        }
    }
}

// ---------------------------------------------------------------------------
// votes[l] = h_l[l] . out_w + out_b ; atomic per-graph sums
// ---------------------------------------------------------------------------
__global__ void votes_kernel(const float* __restrict__ h_l,
                             const float* __restrict__ out_w,
                             const float* __restrict__ out_b,
                             float* __restrict__ votes_out,
                             float* __restrict__ sums) {
    int l = blockIdx.x;
    int d = threadIdx.x;   // 128 threads
    float p = h_l[l * D + d] * out_w[d];
#pragma unroll
    for (int off = 32; off > 0; off >>= 1) p += __shfl_down(p, off, 64);
    __shared__ float ws2[2];
    if ((d & 63) == 0) ws2[d >> 6] = p;
    __syncthreads();
    if (d == 0) {
        float v = ws2[0] + ws2[1] + out_b[0];
        votes_out[l] = v;
        atomicAdd(&sums[l / LITS_PER_GRAPH], v);
    }
}

__global__ void finalize_kernel(const float* __restrict__ sums,
                                float* __restrict__ out0) {
    int b = threadIdx.x;
    if (b < BGR) out0[b] = sums[b] / (float)LITS_PER_GRAPH;
}

// ---------------------------------------------------------------------------
extern "C" void kernel_launch(void* const* d_in, const int* in_sizes, int n_in,
                              void* d_out, int out_size, void* d_ws, size_t ws_size,
                              hipStream_t stream) {
    (void)in_sizes; (void)n_in; (void)out_size; (void)ws_size;

    const float* x_unk  = (const float*)d_in[0];
    const float* C_w    = (const float*)d_in[1];
    const float* C_b    = (const float*)d_in[2];
    const float* Wih_lc = (const float*)d_in[3];
    const float* Whh_lc = (const float*)d_in[4];
    const float* bih_lc = (const float*)d_in[5];
    const float* bhh_lc = (const float*)d_in[6];
    const float* Wih_cl = (const float*)d_in[7];
    const float* Whh_cl = (const float*)d_in[8];
    const float* bih_cl = (const float*)d_in[9];
    const float* bhh_cl = (const float*)d_in[10];
    const float* out_w  = (const float*)d_in[11];
    const float* out_b  = (const float*)d_in[12];
    const int* lit_idx    = (const int*)d_in[13];
    const int* clause_idx = (const int*)d_in[14];
    const int* flip_perm  = (const int*)d_in[16];

    // workspace layout (floats)
    float* F      = (float*)d_ws;
    float* h_lA   = F;                      //  4,096,000
    float* c_l    = F +  4096000;           //  4,096,000
    float* h_c    = F +  8192000;           //  8,192,000
    float* c_c    = F + 16384000;           //  8,192,000
    float* msg_l  = F + 24576000;           //  4,096,000
    float* sums   = F + 28672000;           //  64 (32 used)
    int* counts      = (int*)(F + 28672064);        // NLIT
    int* starts      = counts + NLIT;               // NLIT+1
    int* cursor      = starts + NLIT + 1;           // NLIT
    int* edge_clause = cursor + NLIT;               // NEDGE

    float* out        = (float*)d_out;
    float* out_votes  = out + BGR;
    float* out_hl     = out + BGR + NLIT;   // also used as h_l ping-pong buffer

    // zero-init state (ws is poisoned 0xAA each call)
    hipMemsetAsync(c_l,    0, (size_t)NLIT * D * sizeof(float), stream);
    hipMemsetAsync(c_c,    0, (size_t)NCLA * D * sizeof(float), stream);
    hipMemsetAsync(counts, 0, (size_t)NLIT * sizeof(int), stream);
    hipMemsetAsync(sums,   0, (size_t)BGR * sizeof(float), stream);

    init_hc_kernel<<<(NCLA * D + 255) / 256, 256, 0, stream>>>(h_c, C_w, C_b);

    // CSR build (same work every call; inputs are restored before each launch)
    count_edges_kernel<<<(NEDGE + 255) / 256, 256, 0, stream>>>(lit_idx, counts);
    scan_kernel<<<1, 1024, 0, stream>>>(counts, starts, cursor);
    fill_csr_kernel<<<(NEDGE + 255) / 256, 256, 0, stream>>>(lit_idx, clause_idx,
                                                             cursor, edge_clause);

    // h_l ping-pong: iter0 reads x_unk; writes alternate h_lA / out_hl;
    // 4 iterations -> final h_l lands in out_hl (the d_out region).
    const float* h_old[ITERS] = {x_unk, h_lA, out_hl, h_lA};
    float*       h_new[ITERS] = {h_lA, out_hl, h_lA, out_hl};

    for (int it = 0; it < ITERS; ++it) {
        clause_lstm_kernel<<<NCLA / 64, 512, 0, stream>>>(
            h_old[it], h_c, c_c, Wih_lc, Whh_lc, bih_lc, bhh_lc, lit_idx);
        gather_msg_l_kernel<<<(NLIT * D + 255) / 256, 256, 0, stream>>>(
            h_c, msg_l, starts, edge_clause);
        literal_lstm_kernel<<<NLIT / 64, 512, 0, stream>>>(
            h_old[it], msg_l, h_new[it], c_l, Wih_cl, Whh_cl, bih_cl, bhh_cl,
            flip_perm);
    }

    votes_kernel<<<NLIT, 128, 0, stream>>>(out_hl, out_w, out_b, out_votes, sums);
    finalize_kernel<<<1, 64, 0, stream>>>(sums, out);
}

// Round 2
// 917.714 us; speedup vs baseline: 4.5835x; 4.5835x over previous
//
#include <hip/hip_runtime.h>
#include <hip/hip_bf16.h>

// Problem constants (fixed by setup_inputs)
#define D     128
#define NLIT  32000
#define NCLA  64000
#define KLIT  3
#define NEDGE 192000
#define BGR   32
#define ITERS 4
#define LITS_PER_GRAPH 1000

typedef _Float16 f16x8 __attribute__((ext_vector_type(8)));
typedef float    f32x4 __attribute__((ext_vector_type(4)));

__device__ __forceinline__ float sigf(float x)  { return 1.f / (1.f + __expf(-x)); }
__device__ __forceinline__ float tanhft(float x){ return 1.f - 2.f / (__expf(2.f * x) + 1.f); }

// async 16B global -> LDS (wave-uniform LDS base, lane i lands at base + 16*i)
__device__ __forceinline__ void async_cp16(const void* g, void* l) {
    __builtin_amdgcn_global_load_lds((const __attribute__((address_space(1))) void*)g,
                                     (__attribute__((address_space(3))) void*)l,
                                     16, 0, 0);
}

// ---------------------------------------------------------------------------
// one-time conversions
// ---------------------------------------------------------------------------
__global__ void conv_x_kernel(const float* __restrict__ x, _Float16* __restrict__ o) {
    int t = blockIdx.x * blockDim.x + threadIdx.x;          // NLIT*16
    if (t >= NLIT * 16) return;
    const float* p = x + t * 8;
    f16x8 v;
#pragma unroll
    for (int i = 0; i < 8; ++i) v[i] = (_Float16)p[i];
    *(f16x8*)((_Float16*)o + t * 8) = v;
}

__global__ void init_hc16_kernel(_Float16* __restrict__ h_c,
                                 const float* __restrict__ C_w,
                                 const float* __restrict__ C_b) {
    int t = blockIdx.x * blockDim.x + threadIdx.x;          // NCLA*16
    if (t >= NCLA * 16) return;
    int d0 = (t & 15) * 8;
    f16x8 v;
#pragma unroll
    for (int i = 0; i < 8; ++i) v[i] = (_Float16)(C_w[d0 + i] + C_b[d0 + i]);
    *(f16x8*)(h_c + t * 8) = v;
}

// Wc: 512 x 256 f16  ([n][k], k<128 from Wih, else Whh)
__global__ void conv_wc_kernel(const float* __restrict__ Wih,
                               const float* __restrict__ Whh,
                               _Float16* __restrict__ Wc) {
    int n = blockIdx.x, k = threadIdx.x;                    // 512 x 256
    float v = (k < 128) ? Wih[n * 128 + k] : Whh[n * 128 + k - 128];
    Wc[n * 256 + k] = (_Float16)v;
}

// Wl: 512 x 384 f16  ([n][k], k<256 from Wih, else Whh)
__global__ void conv_wl_kernel(const float* __restrict__ Wih,
                               const float* __restrict__ Whh,
                               _Float16* __restrict__ Wl) {
    int n = blockIdx.x, k = threadIdx.x;                    // 512 x 384
    float v = (k < 256) ? Wih[n * 256 + k] : Whh[n * 128 + k - 256];
    Wl[n * 384 + k] = (_Float16)v;
}

__global__ void conv_bias_kernel(const float* bih_c, const float* bhh_c, float* bc,
                                 const float* bih_l, const float* bhh_l, float* bl) {
    int t = threadIdx.x;                                    // 512
    bc[t] = bih_c[t] + bhh_c[t];
    bl[t] = bih_l[t] + bhh_l[t];
}

// ---------------------------------------------------------------------------
// CSR build: counts -> scan -> fill
// ---------------------------------------------------------------------------
__global__ void count_edges_kernel(const int* __restrict__ lit_idx,
                                   int* __restrict__ counts) {
    int e = blockIdx.x * blockDim.x + threadIdx.x;
    if (e < NEDGE) atomicAdd(&counts[lit_idx[e]], 1);
}

__global__ void scan_kernel(const int* __restrict__ counts,
                            int* __restrict__ starts,
                            int* __restrict__ cursor) {
    __shared__ int ssum[1024];
    int t = threadIdx.x;
    int base = t * 32;
    int s = 0;
    for (int i = 0; i < 32; ++i) {
        int idx = base + i;
        if (idx < NLIT) s += counts[idx];
    }
    ssum[t] = s;
    __syncthreads();
    for (int off = 1; off < 1024; off <<= 1) {
        int v = (t >= off) ? ssum[t - off] : 0;
        __syncthreads();
        ssum[t] += v;
        __syncthreads();
    }
    int run = (t == 0) ? 0 : ssum[t - 1];
    for (int i = 0; i < 32; ++i) {
        int idx = base + i;
        if (idx < NLIT) {
            starts[idx] = run;
            cursor[idx] = run;
            run += counts[idx];
        }
    }
    if (t == 1023) starts[NLIT] = run;
}

__global__ void fill_csr_kernel(const int* __restrict__ lit_idx,
                                const int* __restrict__ clause_idx,
                                int* __restrict__ cursor,
                                int* __restrict__ edge_clause) {
    int e = blockIdx.x * blockDim.x + threadIdx.x;
    if (e < NEDGE) {
        int l = lit_idx[e];
        int pos = atomicAdd(&cursor[l], 1);
        edge_clause[pos] = clause_idx[e];
    }
}

// ---------------------------------------------------------------------------
// msg_l[l][:] = sum over clauses of literal l of h_c16[clause][:]   (f16 io, fp32 acc)
// ---------------------------------------------------------------------------
__global__ void gather_msg_kernel(const _Float16* __restrict__ h_c16,
                                  _Float16* __restrict__ msg16,
                                  const int* __restrict__ starts,
                                  const int* __restrict__ edge_clause) {
    int t = blockIdx.x * blockDim.x + threadIdx.x;          // NLIT*16
    if (t >= NLIT * 16) return;
    int l = t >> 4;
    int off = (t & 15) * 8;
    int s = starts[l], e = starts[l + 1];
    float a[8];
#pragma unroll
    for (int i = 0; i < 8; ++i) a[i] = 0.f;
    for (int j = s; j < e; ++j) {
        f16x8 v = *(const f16x8*)&h_c16[(size_t)edge_clause[j] * D + off];
#pragma unroll
        for (int i = 0; i < 8; ++i) a[i] += (float)v[i];
    }
    f16x8 o;
#pragma unroll
    for (int i = 0; i < 8; ++i) o[i] = (_Float16)a[i];
    *(f16x8*)&msg16[(size_t)l * D + off] = o;
}

// ---------------------------------------------------------------------------
// Clause LSTM (MFMA): rows 64/block, d-half per block (c = bx&1).
// A = [gather3(h_l) | h_c_old], K=256. Wave w owns coltile u=w across all 4
// row-tiles and all 4 gates -> full LSTM quadruple in registers.
// ---------------------------------------------------------------------------
__global__ __launch_bounds__(256, 3)
void clause_mfma_kernel(const _Float16* __restrict__ h_l16,   // NLIT x 128
                        const _Float16* __restrict__ h_c_old, // NCLA x 128
                        _Float16* __restrict__ h_c_new,       // NCLA x 128
                        float* __restrict__ c_c,              // NCLA x 128
                        const _Float16* __restrict__ Wc,      // 512 x 256
                        const float* __restrict__ bc,         // 512
                        const int* __restrict__ lit_idx) {
    __shared__ _Float16 Wl[256 * 32];
    __shared__ _Float16 Al[64 * 32];
    __shared__ int      lidx[192];

    const int tid  = threadIdx.x;
    const int w    = tid >> 6;
    const int lane = tid & 63;
    const int qd   = lane >> 4;
    const int ln   = lane & 15;
    const int bx   = blockIdx.x;
    const int c    = bx & 1;             // d-half: cols [64c, 64c+64)
    const int row0 = (bx >> 1) * 64;

    if (tid < 192) lidx[tid] = lit_idx[row0 * 3 + tid];

    f32x4 acc[4][4];
#pragma unroll
    for (int R = 0; R < 4; ++R)
#pragma unroll
        for (int g = 0; g < 4; ++g) { acc[R][g][0]=0.f; acc[R][g][1]=0.f; acc[R][g][2]=0.f; acc[R][g][3]=0.f; }

    for (int ch = 0; ch < 8; ++ch) {
        const int k0 = ch * 32;
        __syncthreads();
        // ---- W stage: wave w stages gate-w rows (64 rows x 64B) via async
        {
            const int nbase = w * 128 + c * 64;   // global W row for qloc=0
#pragma unroll
            for (int j = 0; j < 4; ++j) {
                int qloc = 16 * j + (lane >> 2);
                const _Float16* g = Wc + (nbase + qloc) * 256 + k0 + (lane & 3) * 8;
                async_cp16(g, &Wl[(64 * w + 16 * j) * 32]);
            }
        }
        // ---- A stage
        if (ch < 4) {
            // fused 3-literal gather: thread -> (m = tid>>2, off = (tid&3)*8)
            int m   = tid >> 2;
            int off = (tid & 3) * 8;
            int kk  = k0 + off;
            f16x8 v0 = *(const f16x8*)&h_l16[(size_t)lidx[3 * m + 0] * D + kk];
            f16x8 v1 = *(const f16x8*)&h_l16[(size_t)lidx[3 * m + 1] * D + kk];
            f16x8 v2 = *(const f16x8*)&h_l16[(size_t)lidx[3 * m + 2] * D + kk];
            f16x8 o;
#pragma unroll
            for (int i = 0; i < 8; ++i) o[i] = (_Float16)((float)v0[i] + (float)v1[i] + (float)v2[i]);
            *(f16x8*)&Al[m * 32 + off] = o;
        } else {
            // copy own h_c rows: wave w stages rows 16w..16w+15
            int m = 16 * w + (lane >> 2);
            const _Float16* g = h_c_old + (size_t)(row0 + m) * D + (k0 - 128) + (lane & 3) * 8;
            async_cp16(g, &Al[(16 * w) * 32]);
        }
        __syncthreads();
        // ---- fragments + MFMA
        f16x8 af[4], bf[4];
#pragma unroll
        for (int R = 0; R < 4; ++R)
            af[R] = *(const f16x8*)&Al[(16 * R + ln) * 32 + qd * 8];
#pragma unroll
        for (int g = 0; g < 4; ++g)
            bf[g] = *(const f16x8*)&Wl[(64 * g + 16 * w + ln) * 32 + qd * 8];
#pragma unroll
        for (int R = 0; R < 4; ++R)
#pragma unroll
            for (int g = 0; g < 4; ++g)
                acc[R][g] = __builtin_amdgcn_mfma_f32_16x16x32_f16(af[R], bf[g], acc[R][g], 0, 0, 0);
    }

    // ---- fused LSTM epilogue (full i,f,g,o quadruple in registers)
    const int dcol = c * 64 + 16 * w + ln;     // 0..127
    const float b0 = bc[dcol], b1 = bc[128 + dcol], b2 = bc[256 + dcol], b3 = bc[384 + dcol];
#pragma unroll
    for (int R = 0; R < 4; ++R) {
#pragma unroll
        for (int r = 0; r < 4; ++r) {
            int m = row0 + 16 * R + qd * 4 + r;
            size_t idx = (size_t)m * D + dcol;
            float gi = acc[R][0][r] + b0;
            float gf = acc[R][1][r] + b1;
            float gg = acc[R][2][r] + b2;
            float go = acc[R][3][r] + b3;
            float co = c_c[idx];
            float cn = sigf(gf) * co + sigf(gi) * tanhft(gg);
            float h  = sigf(go) * tanhft(cn);
            c_c[idx]     = cn;
            h_c_new[idx] = (_Float16)h;
        }
    }
}

// ---------------------------------------------------------------------------
// Literal LSTM (MFMA): A = [msg_l | h_old[flip] | h_old], K=384.
// All A staging is copy-type -> async global_load_lds.
// ---------------------------------------------------------------------------
__global__ __launch_bounds__(256, 3)
void literal_mfma_kernel(const _Float16* __restrict__ h_old16, // NLIT x 128
                         const _Float16* __restrict__ msg16,   // NLIT x 128
                         _Float16* __restrict__ h_new16,       // NLIT x 128
                         float* __restrict__ h32,              // optional fp32 out (final iter)
                         float* __restrict__ c_l,              // NLIT x 128
                         const _Float16* __restrict__ Wl384,   // 512 x 384
                         const float* __restrict__ bl,         // 512
                         const int* __restrict__ flip_perm) {
    __shared__ _Float16 Wl[256 * 32];
    __shared__ _Float16 Al[64 * 32];
    __shared__ int      flip_s[64];

    const int tid  = threadIdx.x;
    const int w    = tid >> 6;
    const int lane = tid & 63;
    const int qd   = lane >> 4;
    const int ln   = lane & 15;
    const int bx   = blockIdx.x;
    const int c    = bx & 1;
    const int row0 = (bx >> 1) * 64;

    if (tid < 64) flip_s[tid] = flip_perm[row0 + tid];

    f32x4 acc[4][4];
#pragma unroll
    for (int R = 0; R < 4; ++R)
#pragma unroll
        for (int g = 0; g < 4; ++g) { acc[R][g][0]=0.f; acc[R][g][1]=0.f; acc[R][g][2]=0.f; acc[R][g][3]=0.f; }

    for (int ch = 0; ch < 12; ++ch) {
        const int k0 = ch * 32;
        __syncthreads();
        // ---- W stage
        {
            const int nbase = w * 128 + c * 64;
#pragma unroll
            for (int j = 0; j < 4; ++j) {
                int qloc = 16 * j + (lane >> 2);
                const _Float16* g = Wl384 + (nbase + qloc) * 384 + k0 + (lane & 3) * 8;
                async_cp16(g, &Wl[(64 * w + 16 * j) * 32]);
            }
        }
        // ---- A stage (all copies): wave w stages rows 16w..16w+15
        {
            int m   = 16 * w + (lane >> 2);
            int sub = (lane & 3) * 8;
            const _Float16* g;
            if (ch < 4)       g = msg16   + (size_t)(row0 + m) * D + k0 + sub;
            else if (ch < 8)  g = h_old16 + (size_t)flip_s[m] * D + (k0 - 128) + sub;
            else              g = h_old16 + (size_t)(row0 + m) * D + (k0 - 256) + sub;
            async_cp16(g, &Al[(16 * w) * 32]);
        }
        __syncthreads();
        // ---- fragments + MFMA
        f16x8 af[4], bf[4];
#pragma unroll
        for (int R = 0; R < 4; ++R)
            af[R] = *(const f16x8*)&Al[(16 * R + ln) * 32 + qd * 8];
#pragma unroll
        for (int g = 0; g < 4; ++g)
            bf[g] = *(const f16x8*)&Wl[(64 * g + 16 * w + ln) * 32 + qd * 8];
#pragma unroll
        for (int R = 0; R < 4; ++R)
#pragma unroll
            for (int g = 0; g < 4; ++g)
                acc[R][g] = __builtin_amdgcn_mfma_f32_16x16x32_f16(af[R], bf[g], acc[R][g], 0, 0, 0);
    }

    const int dcol = c * 64 + 16 * w + ln;
    const float b0 = bl[dcol], b1 = bl[128 + dcol], b2 = bl[256 + dcol], b3 = bl[384 + dcol];
#pragma unroll
    for (int R = 0; R < 4; ++R) {
#pragma unroll
        for (int r = 0; r < 4; ++r) {
            int m = row0 + 16 * R + qd * 4 + r;
            size_t idx = (size_t)m * D + dcol;
            float gi = acc[R][0][r] + b0;
            float gf = acc[R][1][r] + b1;
            float gg = acc[R][2][r] + b2;
            float go = acc[R][3][r] + b3;
            float co = c_l[idx];
            float cn = sigf(gf) * co + sigf(gi) * tanhft(gg);
            float h  = sigf(go) * tanhft(cn);
            c_l[idx]     = cn;
            h_new16[idx] = (_Float16)h;
            if (h32) h32[idx] = h;
        }
    }
}

// ---------------------------------------------------------------------------
// votes + per-graph mean
// ---------------------------------------------------------------------------
__global__ void votes_kernel(const float* __restrict__ h_l,
                             const float* __restrict__ out_w,
                             const float* __restrict__ out_b,
                             float* __restrict__ votes_out,
                             float* __restrict__ sums) {
    int l = blockIdx.x;
    int d = threadIdx.x;   // 128 threads
    float p = h_l[(size_t)l * D + d] * out_w[d];
#pragma unroll
    for (int off = 32; off > 0; off >>= 1) p += __shfl_down(p, off, 64);
    __shared__ float ws2[2];
    if ((d & 63) == 0) ws2[d >> 6] = p;
    __syncthreads();
    if (d == 0) {
        float v = ws2[0] + ws2[1] + out_b[0];
        votes_out[l] = v;
        atomicAdd(&sums[l / LITS_PER_GRAPH], v);
    }
}

__global__ void finalize_kernel(const float* __restrict__ sums,
                                float* __restrict__ out0) {
    int b = threadIdx.x;
    if (b < BGR) out0[b] = sums[b] / (float)LITS_PER_GRAPH;
}

// ---------------------------------------------------------------------------
extern "C" void kernel_launch(void* const* d_in, const int* in_sizes, int n_in,
                              void* d_out, int out_size, void* d_ws, size_t ws_size,
                              hipStream_t stream) {
    (void)in_sizes; (void)n_in; (void)out_size; (void)ws_size;

    const float* x_unk  = (const float*)d_in[0];
    const float* C_w    = (const float*)d_in[1];
    const float* C_b    = (const float*)d_in[2];
    const float* Wih_lc = (const float*)d_in[3];
    const float* Whh_lc = (const float*)d_in[4];
    const float* bih_lc = (const float*)d_in[5];
    const float* bhh_lc = (const float*)d_in[6];
    const float* Wih_cl = (const float*)d_in[7];
    const float* Whh_cl = (const float*)d_in[8];
    const float* bih_cl = (const float*)d_in[9];
    const float* bhh_cl = (const float*)d_in[10];
    const float* out_w  = (const float*)d_in[11];
    const float* out_b  = (const float*)d_in[12];
    const int* lit_idx    = (const int*)d_in[13];
    const int* clause_idx = (const int*)d_in[14];
    const int* flip_perm  = (const int*)d_in[16];

    // ---- workspace layout (bytes, 256-aligned chunks)
    char* W = (char*)d_ws;
    size_t off = 0;
    auto alloc = [&](size_t bytes) { char* p = W + off; off = (off + bytes + 255) & ~(size_t)255; return p; };
    _Float16* h_l16_0 = (_Float16*)alloc((size_t)NLIT * D * 2);
    _Float16* h_l16_1 = (_Float16*)alloc((size_t)NLIT * D * 2);
    _Float16* h_c16_0 = (_Float16*)alloc((size_t)NCLA * D * 2);
    _Float16* h_c16_1 = (_Float16*)alloc((size_t)NCLA * D * 2);
    _Float16* msg16   = (_Float16*)alloc((size_t)NLIT * D * 2);
    float*    c_l     = (float*)  alloc((size_t)NLIT * D * 4);
    float*    c_c     = (float*)  alloc((size_t)NCLA * D * 4);
    _Float16* Wc16    = (_Float16*)alloc(512 * 256 * 2);
    _Float16* Wl16    = (_Float16*)alloc(512 * 384 * 2);
    float*    bc      = (float*)  alloc(512 * 4);
    float*    bl      = (float*)  alloc(512 * 4);
    float*    sums    = (float*)  alloc(BGR * 4);
    int* counts       = (int*)alloc((size_t)NLIT * 4);
    int* starts       = (int*)alloc((size_t)(NLIT + 1) * 4);
    int* cursor       = (int*)alloc((size_t)NLIT * 4);
    int* edge_clause  = (int*)alloc((size_t)NEDGE * 4);

    float* out       = (float*)d_out;
    float* out_votes = out + BGR;
    float* out_hl    = out + BGR + NLIT;

    // ---- zero-init state
    hipMemsetAsync(c_l,    0, (size_t)NLIT * D * 4, stream);
    hipMemsetAsync(c_c,    0, (size_t)NCLA * D * 4, stream);
    hipMemsetAsync(counts, 0, (size_t)NLIT * 4, stream);
    hipMemsetAsync(sums,   0, (size_t)BGR * 4, stream);

    // ---- one-time conversions
    conv_x_kernel<<<(NLIT * 16 + 255) / 256, 256, 0, stream>>>(x_unk, h_l16_0);
    init_hc16_kernel<<<(NCLA * 16 + 255) / 256, 256, 0, stream>>>(h_c16_0, C_w, C_b);
    conv_wc_kernel<<<512, 256, 0, stream>>>(Wih_lc, Whh_lc, Wc16);
    conv_wl_kernel<<<512, 384, 0, stream>>>(Wih_cl, Whh_cl, Wl16);
    conv_bias_kernel<<<1, 512, 0, stream>>>(bih_lc, bhh_lc, bc, bih_cl, bhh_cl, bl);

    // ---- CSR build
    count_edges_kernel<<<(NEDGE + 255) / 256, 256, 0, stream>>>(lit_idx, counts);
    scan_kernel<<<1, 1024, 0, stream>>>(counts, starts, cursor);
    fill_csr_kernel<<<(NEDGE + 255) / 256, 256, 0, stream>>>(lit_idx, clause_idx,
                                                             cursor, edge_clause);

    // ---- message-passing iterations (h_l and h_c ping-pong in f16)
    const _Float16* hl_old[ITERS] = {h_l16_0, h_l16_1, h_l16_0, h_l16_1};
    _Float16*       hl_new[ITERS] = {h_l16_1, h_l16_0, h_l16_1, h_l16_0};
    const _Float16* hc_old[ITERS] = {h_c16_0, h_c16_1, h_c16_0, h_c16_1};
    _Float16*       hc_new[ITERS] = {h_c16_1, h_c16_0, h_c16_1, h_c16_0};

    for (int it = 0; it < ITERS; ++it) {
        clause_mfma_kernel<<<(NCLA / 64) * 2, 256, 0, stream>>>(
            hl_old[it], hc_old[it], hc_new[it], c_c, Wc16, bc, lit_idx);
        gather_msg_kernel<<<(NLIT * 16 + 255) / 256, 256, 0, stream>>>(
            hc_new[it], msg16, starts, edge_clause);
        literal_mfma_kernel<<<(NLIT / 64) * 2, 256, 0, stream>>>(
            hl_old[it], msg16, hl_new[it],
            (it == ITERS - 1) ? out_hl : (float*)nullptr,
            c_l, Wl16, bl, flip_perm);
    }

    votes_kernel<<<NLIT, 128, 0, stream>>>(out_hl, out_w, out_b, out_votes, sums);
    finalize_kernel<<<1, 64, 0, stream>>>(sums, out);
}

// Round 3
// 615.760 us; speedup vs baseline: 6.8312x; 1.4904x over previous
//
#include <hip/hip_runtime.h>
#include <hip/hip_bf16.h>

// Problem constants (fixed by setup_inputs)
#define D     128
#define NLIT  32000
#define NCLA  64000
#define KLIT  3
#define NEDGE 192000
#define BGR   32
#define ITERS 4
#define LITS_PER_GRAPH 1000

typedef _Float16 f16x8 __attribute__((ext_vector_type(8)));
typedef float    f32x4 __attribute__((ext_vector_type(4)));

__device__ __forceinline__ float sigf(float x)  { return 1.f / (1.f + __expf(-x)); }
__device__ __forceinline__ float tanhft(float x){ return 1.f - 2.f / (__expf(2.f * x) + 1.f); }

// async 16B global -> LDS (wave-uniform LDS base, lane i lands at base + 16*i)
__device__ __forceinline__ void async_cp16(const void* g, void* l) {
    __builtin_amdgcn_global_load_lds((const __attribute__((address_space(1))) void*)g,
                                     (__attribute__((address_space(3))) void*)l,
                                     16, 0, 0);
}

// ---------------------------------------------------------------------------
// one-time conversions
// ---------------------------------------------------------------------------
__global__ void conv_x_kernel(const float* __restrict__ x, _Float16* __restrict__ o) {
    int t = blockIdx.x * blockDim.x + threadIdx.x;          // NLIT*16
    if (t >= NLIT * 16) return;
    const float* p = x + t * 8;
    f16x8 v;
#pragma unroll
    for (int i = 0; i < 8; ++i) v[i] = (_Float16)p[i];
    *(f16x8*)((_Float16*)o + t * 8) = v;
}

__global__ void init_hc16_kernel(_Float16* __restrict__ h_c,
                                 const float* __restrict__ C_w,
                                 const float* __restrict__ C_b) {
    int t = blockIdx.x * blockDim.x + threadIdx.x;          // NCLA*16
    if (t >= NCLA * 16) return;
    int d0 = (t & 15) * 8;
    f16x8 v;
#pragma unroll
    for (int i = 0; i < 8; ++i) v[i] = (_Float16)(C_w[d0 + i] + C_b[d0 + i]);
    *(f16x8*)(h_c + t * 8) = v;
}

// Wc: 512 x 256 f16  ([n][k], k<128 from Wih, else Whh)
__global__ void conv_wc_kernel(const float* __restrict__ Wih,
                               const float* __restrict__ Whh,
                               _Float16* __restrict__ Wc) {
    int n = blockIdx.x, k = threadIdx.x;                    // 512 x 256
    float v = (k < 128) ? Wih[n * 128 + k] : Whh[n * 128 + k - 128];
    Wc[n * 256 + k] = (_Float16)v;
}

// Wl: 512 x 384 f16  ([n][k], k<256 from Wih, else Whh)
__global__ void conv_wl_kernel(const float* __restrict__ Wih,
                               const float* __restrict__ Whh,
                               _Float16* __restrict__ Wl) {
    int n = blockIdx.x, k = threadIdx.x;                    // 512 x 384
    float v = (k < 256) ? Wih[n * 256 + k] : Whh[n * 128 + k - 256];
    Wl[n * 384 + k] = (_Float16)v;
}

__global__ void conv_bias_kernel(const float* bih_c, const float* bhh_c, float* bc,
                                 const float* bih_l, const float* bhh_l, float* bl) {
    int t = threadIdx.x;                                    // 512
    bc[t] = bih_c[t] + bhh_c[t];
    bl[t] = bih_l[t] + bhh_l[t];
}

// ---------------------------------------------------------------------------
// CSR build: counts -> scan -> fill
// ---------------------------------------------------------------------------
__global__ void count_edges_kernel(const int* __restrict__ lit_idx,
                                   int* __restrict__ counts) {
    int e = blockIdx.x * blockDim.x + threadIdx.x;
    if (e < NEDGE) atomicAdd(&counts[lit_idx[e]], 1);
}

__global__ void scan_kernel(const int* __restrict__ counts,
                            int* __restrict__ starts,
                            int* __restrict__ cursor) {
    __shared__ int ssum[1024];
    int t = threadIdx.x;
    int base = t * 32;
    int s = 0;
    for (int i = 0; i < 32; ++i) {
        int idx = base + i;
        if (idx < NLIT) s += counts[idx];
    }
    ssum[t] = s;
    __syncthreads();
    for (int off = 1; off < 1024; off <<= 1) {
        int v = (t >= off) ? ssum[t - off] : 0;
        __syncthreads();
        ssum[t] += v;
        __syncthreads();
    }
    int run = (t == 0) ? 0 : ssum[t - 1];
    for (int i = 0; i < 32; ++i) {
        int idx = base + i;
        if (idx < NLIT) {
            starts[idx] = run;
            cursor[idx] = run;
            run += counts[idx];
        }
    }
    if (t == 1023) starts[NLIT] = run;
}

__global__ void fill_csr_kernel(const int* __restrict__ lit_idx,
                                const int* __restrict__ clause_idx,
                                int* __restrict__ cursor,
                                int* __restrict__ edge_clause) {
    int e = blockIdx.x * blockDim.x + threadIdx.x;
    if (e < NEDGE) {
        int l = lit_idx[e];
        int pos = atomicAdd(&cursor[l], 1);
        edge_clause[pos] = clause_idx[e];
    }
}

// ---------------------------------------------------------------------------
// msg_l[l][:] = sum over clauses of literal l of h_c16[clause][:]   (f16 io, fp32 acc)
// ---------------------------------------------------------------------------
__global__ void gather_msg_kernel(const _Float16* __restrict__ h_c16,
                                  _Float16* __restrict__ msg16,
                                  const int* __restrict__ starts,
                                  const int* __restrict__ edge_clause) {
    int t = blockIdx.x * blockDim.x + threadIdx.x;          // NLIT*16
    if (t >= NLIT * 16) return;
    int l = t >> 4;
    int off = (t & 15) * 8;
    int s = starts[l], e = starts[l + 1];
    float a[8];
#pragma unroll
    for (int i = 0; i < 8; ++i) a[i] = 0.f;
    for (int j = s; j < e; ++j) {
        f16x8 v = *(const f16x8*)&h_c16[(size_t)edge_clause[j] * D + off];
#pragma unroll
        for (int i = 0; i < 8; ++i) a[i] += (float)v[i];
    }
    f16x8 o;
#pragma unroll
    for (int i = 0; i < 8; ++i) o[i] = (_Float16)a[i];
    *(f16x8*)&msg16[(size_t)l * D + off] = o;
}

// ---------------------------------------------------------------------------
// Clause LSTM (MFMA): rows 64/block, d-half per block (c = bx&1).
// A = [gather3(h_l) | h_c_old], K=256. Wave w owns coltile u=w across all 4
// row-tiles and all 4 gates -> full LSTM quadruple in registers.
// ---------------------------------------------------------------------------
__global__ __launch_bounds__(256, 3)
void clause_mfma_kernel(const _Float16* __restrict__ h_l16,   // NLIT x 128
                        const _Float16* __restrict__ h_c_old, // NCLA x 128
                        _Float16* __restrict__ h_c_new,       // NCLA x 128
                        float* __restrict__ c_c,              // NCLA x 128
                        const _Float16* __restrict__ Wc,      // 512 x 256
                        const float* __restrict__ bc,         // 512
                        const int* __restrict__ lit_idx) {
    __shared__ _Float16 Wl[256 * 32];
    __shared__ _Float16 Al[64 * 32];
    __shared__ int      lidx[192];

    const int tid  = threadIdx.x;
    const int w    = tid >> 6;
    const int lane = tid & 63;
    const int qd   = lane >> 4;
    const int ln   = lane & 15;
    const int bx   = blockIdx.x;
    const int c    = bx & 1;             // d-half: cols [64c, 64c+64)
    const int row0 = (bx >> 1) * 64;

    if (tid < 192) lidx[tid] = lit_idx[row0 * 3 + tid];

    f32x4 acc[4][4];
#pragma unroll
    for (int R = 0; R < 4; ++R)
#pragma unroll
        for (int g = 0; g < 4; ++g) { acc[R][g][0]=0.f; acc[R][g][1]=0.f; acc[R][g][2]=0.f; acc[R][g][3]=0.f; }

    for (int ch = 0; ch < 8; ++ch) {
        const int k0 = ch * 32;
        __syncthreads();
        // ---- W stage: wave w stages gate-w rows (64 rows x 64B) via async
        {
            const int nbase = w * 128 + c * 64;   // global W row for qloc=0
#pragma unroll
            for (int j = 0; j < 4; ++j) {
                int qloc = 16 * j + (lane >> 2);
                const _Float16* g = Wc + (nbase + qloc) * 256 + k0 + (lane & 3) * 8;
                async_cp16(g, &Wl[(64 * w + 16 * j) * 32]);
            }
        }
        // ---- A stage
        if (ch < 4) {
            // fused 3-literal gather: thread -> (m = tid>>2, off = (tid&3)*8)
            int m   = tid >> 2;
            int off = (tid & 3) * 8;
            int kk  = k0 + off;
            f16x8 v0 = *(const f16x8*)&h_l16[(size_t)lidx[3 * m + 0] * D + kk];
            f16x8 v1 = *(const f16x8*)&h_l16[(size_t)lidx[3 * m + 1] * D + kk];
            f16x8 v2 = *(const f16x8*)&h_l16[(size_t)lidx[3 * m + 2] * D + kk];
            f16x8 o;
#pragma unroll
            for (int i = 0; i < 8; ++i) o[i] = (_Float16)((float)v0[i] + (float)v1[i] + (float)v2[i]);
            *(f16x8*)&Al[m * 32 + off] = o;
        } else {
            // copy own h_c rows: wave w stages rows 16w..16w+15
            int m = 16 * w + (lane >> 2);
            const _Float16* g = h_c_old + (size_t)(row0 + m) * D + (k0 - 128) + (lane & 3) * 8;
            async_cp16(g, &Al[(16 * w) * 32]);
        }
        __syncthreads();
        // ---- fragments + MFMA
        f16x8 af[4], bf[4];
#pragma unroll
        for (int R = 0; R < 4; ++R)
            af[R] = *(const f16x8*)&Al[(16 * R + ln) * 32 + qd * 8];
#pragma unroll
        for (int g = 0; g < 4; ++g)
            bf[g] = *(const f16x8*)&Wl[(64 * g + 16 * w + ln) * 32 + qd * 8];
#pragma unroll
        for (int R = 0; R < 4; ++R)
#pragma unroll
            for (int g = 0; g < 4; ++g)
                acc[R][g] = __builtin_amdgcn_mfma_f32_16x16x32_f16(af[R], bf[g], acc[R][g], 0, 0, 0);
    }

    // ---- fused LSTM epilogue (full i,f,g,o quadruple in registers)
    const int dcol = c * 64 + 16 * w + ln;     // 0..127
    const float b0 = bc[dcol], b1 = bc[128 + dcol], b2 = bc[256 + dcol], b3 = bc[384 + dcol];
#pragma unroll
    for (int R = 0; R < 4; ++R) {
#pragma unroll
        for (int r = 0; r < 4; ++r) {
            int m = row0 + 16 * R + qd * 4 + r;
            size_t idx = (size_t)m * D + dcol;
            float gi = acc[R][0][r] + b0;
            float gf = acc[R][1][r] + b1;
            float gg = acc[R][2][r] + b2;
            float go = acc[R][3][r] + b3;
            float co = c_c[idx];
            float cn = sigf(gf) * co + sigf(gi) * tanhft(gg);
            float h  = sigf(go) * tanhft(cn);
            c_c[idx]     = cn;
            h_c_new[idx] = (_Float16)h;
        }
    }
}

// ---------------------------------------------------------------------------
// Literal LSTM (MFMA): A = [msg_l | h_old[flip] | h_old], K=384.
// All A staging is copy-type -> async global_load_lds.
// ---------------------------------------------------------------------------
__global__ __launch_bounds__(256, 3)
void literal_mfma_kernel(const _Float16* __restrict__ h_old16, // NLIT x 128
                         const _Float16* __restrict__ msg16,   // NLIT x 128
                         _Float16* __restrict__ h_new16,       // NLIT x 128
                         float* __restrict__ h32,              // optional fp32 out (final iter)
                         float* __restrict__ c_l,              // NLIT x 128
                         const _Float16* __restrict__ Wl384,   // 512 x 384
                         const float* __restrict__ bl,         // 512
                         const int* __restrict__ flip_perm) {
    __shared__ _Float16 Wl[256 * 32];
    __shared__ _Float16 Al[64 * 32];
    __shared__ int      flip_s[64];

    const int tid  = threadIdx.x;
    const int w    = tid >> 6;
    const int lane = tid & 63;
    const int qd   = lane >> 4;
    const int ln   = lane & 15;
    const int bx   = blockIdx.x;
    const int c    = bx & 1;
    const int row0 = (bx >> 1) * 64;

    if (tid < 64) flip_s[tid] = flip_perm[row0 + tid];

    f32x4 acc[4][4];
#pragma unroll
    for (int R = 0; R < 4; ++R)
#pragma unroll
        for (int g = 0; g < 4; ++g) { acc[R][g][0]=0.f; acc[R][g][1]=0.f; acc[R][g][2]=0.f; acc[R][g][3]=0.f; }

    for (int ch = 0; ch < 12; ++ch) {
        const int k0 = ch * 32;
        __syncthreads();
        // ---- W stage
        {
            const int nbase = w * 128 + c * 64;
#pragma unroll
            for (int j = 0; j < 4; ++j) {
                int qloc = 16 * j + (lane >> 2);
                const _Float16* g = Wl384 + (nbase + qloc) * 384 + k0 + (lane & 3) * 8;
                async_cp16(g, &Wl[(64 * w + 16 * j) * 32]);
            }
        }
        // ---- A stage (all copies): wave w stages rows 16w..16w+15
        {
            int m   = 16 * w + (lane >> 2);
            int sub = (lane & 3) * 8;
            const _Float16* g;
            if (ch < 4)       g = msg16   + (size_t)(row0 + m) * D + k0 + sub;
            else if (ch < 8)  g = h_old16 + (size_t)flip_s[m] * D + (k0 - 128) + sub;
            else              g = h_old16 + (size_t)(row0 + m) * D + (k0 - 256) + sub;
            async_cp16(g, &Al[(16 * w) * 32]);
        }
        __syncthreads();
        // ---- fragments + MFMA
        f16x8 af[4], bf[4];
#pragma unroll
        for (int R = 0; R < 4; ++R)
            af[R] = *(const f16x8*)&Al[(16 * R + ln) * 32 + qd * 8];
#pragma unroll
        for (int g = 0; g < 4; ++g)
            bf[g] = *(const f16x8*)&Wl[(64 * g + 16 * w + ln) * 32 + qd * 8];
#pragma unroll
        for (int R = 0; R < 4; ++R)
#pragma unroll
            for (int g = 0; g < 4; ++g)
                acc[R][g] = __builtin_amdgcn_mfma_f32_16x16x32_f16(af[R], bf[g], acc[R][g], 0, 0, 0);
    }

    const int dcol = c * 64 + 16 * w + ln;
    const float b0 = bl[dcol], b1 = bl[128 + dcol], b2 = bl[256 + dcol], b3 = bl[384 + dcol];
#pragma unroll
    for (int R = 0; R < 4; ++R) {
#pragma unroll
        for (int r = 0; r < 4; ++r) {
            int m = row0 + 16 * R + qd * 4 + r;
            size_t idx = (size_t)m * D + dcol;
            float gi = acc[R][0][r] + b0;
            float gf = acc[R][1][r] + b1;
            float gg = acc[R][2][r] + b2;
            float go = acc[R][3][r] + b3;
            float co = c_l[idx];
            float cn = sigf(gf) * co + sigf(gi) * tanhft(gg);
            float h  = sigf(go) * tanhft(cn);
            c_l[idx]     = cn;
            h_new16[idx] = (_Float16)h;
            if (h32) h32[idx] = h;
        }
    }
}

// ---------------------------------------------------------------------------
// votes stage 1: one wave per literal, no atomics.
// lane reads float2 of the row (wave covers the full 512B row, coalesced),
// dot with out_w, shuffle-reduce, lane 0 writes votes[l].
// ---------------------------------------------------------------------------
__global__ __launch_bounds__(256)
void votes_stage1_kernel(const float* __restrict__ h_l,
                         const float* __restrict__ out_w,
                         const float* __restrict__ out_b,
                         float* __restrict__ votes_out) {
    int w    = threadIdx.x >> 6;            // wave in block
    int lane = threadIdx.x & 63;
    int l    = blockIdx.x * 4 + w;          // grid = NLIT/4
    if (l >= NLIT) return;
    const float2 v = *(const float2*)&h_l[(size_t)l * D + lane * 2];
    const float2 ww = *(const float2*)&out_w[lane * 2];
    float p = v.x * ww.x + v.y * ww.y;
#pragma unroll
    for (int off = 32; off > 0; off >>= 1) p += __shfl_down(p, off, 64);
    if (lane == 0) votes_out[l] = p + out_b[0];
}

// votes stage 2: one block per graph, sum 1000 contiguous votes -> mean
__global__ __launch_bounds__(256)
void votes_stage2_kernel(const float* __restrict__ votes,
                         float* __restrict__ out0) {
    int b = blockIdx.x;                     // 32 graphs
    int t = threadIdx.x;
    const float* base = votes + (size_t)b * LITS_PER_GRAPH;
    float s = 0.f;
    for (int i = t; i < LITS_PER_GRAPH; i += 256) s += base[i];
#pragma unroll
    for (int off = 32; off > 0; off >>= 1) s += __shfl_down(s, off, 64);
    __shared__ float ws[4];
    if ((t & 63) == 0) ws[t >> 6] = s;
    __syncthreads();
    if (t == 0) out0[b] = (ws[0] + ws[1] + ws[2] + ws[3]) / (float)LITS_PER_GRAPH;
}

// ---------------------------------------------------------------------------
extern "C" void kernel_launch(void* const* d_in, const int* in_sizes, int n_in,
                              void* d_out, int out_size, void* d_ws, size_t ws_size,
                              hipStream_t stream) {
    (void)in_sizes; (void)n_in; (void)out_size; (void)ws_size;

    const float* x_unk  = (const float*)d_in[0];
    const float* C_w    = (const float*)d_in[1];
    const float* C_b    = (const float*)d_in[2];
    const float* Wih_lc = (const float*)d_in[3];
    const float* Whh_lc = (const float*)d_in[4];
    const float* bih_lc = (const float*)d_in[5];
    const float* bhh_lc = (const float*)d_in[6];
    const float* Wih_cl = (const float*)d_in[7];
    const float* Whh_cl = (const float*)d_in[8];
    const float* bih_cl = (const float*)d_in[9];
    const float* bhh_cl = (const float*)d_in[10];
    const float* out_w  = (const float*)d_in[11];
    const float* out_b  = (const float*)d_in[12];
    const int* lit_idx    = (const int*)d_in[13];
    const int* clause_idx = (const int*)d_in[14];
    const int* flip_perm  = (const int*)d_in[16];

    // ---- workspace layout (bytes, 256-aligned chunks)
    char* W = (char*)d_ws;
    size_t off = 0;
    auto alloc = [&](size_t bytes) { char* p = W + off; off = (off + bytes + 255) & ~(size_t)255; return p; };
    _Float16* h_l16_0 = (_Float16*)alloc((size_t)NLIT * D * 2);
    _Float16* h_l16_1 = (_Float16*)alloc((size_t)NLIT * D * 2);
    _Float16* h_c16_0 = (_Float16*)alloc((size_t)NCLA * D * 2);
    _Float16* h_c16_1 = (_Float16*)alloc((size_t)NCLA * D * 2);
    _Float16* msg16   = (_Float16*)alloc((size_t)NLIT * D * 2);
    float*    c_l     = (float*)  alloc((size_t)NLIT * D * 4);
    float*    c_c     = (float*)  alloc((size_t)NCLA * D * 4);
    _Float16* Wc16    = (_Float16*)alloc(512 * 256 * 2);
    _Float16* Wl16    = (_Float16*)alloc(512 * 384 * 2);
    float*    bc      = (float*)  alloc(512 * 4);
    float*    bl      = (float*)  alloc(512 * 4);
    int* counts       = (int*)alloc((size_t)NLIT * 4);
    int* starts       = (int*)alloc((size_t)(NLIT + 1) * 4);
    int* cursor       = (int*)alloc((size_t)NLIT * 4);
    int* edge_clause  = (int*)alloc((size_t)NEDGE * 4);

    float* out       = (float*)d_out;
    float* out_votes = out + BGR;
    float* out_hl    = out + BGR + NLIT;

    // ---- zero-init state
    hipMemsetAsync(c_l,    0, (size_t)NLIT * D * 4, stream);
    hipMemsetAsync(c_c,    0, (size_t)NCLA * D * 4, stream);
    hipMemsetAsync(counts, 0, (size_t)NLIT * 4, stream);

    // ---- one-time conversions
    conv_x_kernel<<<(NLIT * 16 + 255) / 256, 256, 0, stream>>>(x_unk, h_l16_0);
    init_hc16_kernel<<<(NCLA * 16 + 255) / 256, 256, 0, stream>>>(h_c16_0, C_w, C_b);
    conv_wc_kernel<<<512, 256, 0, stream>>>(Wih_lc, Whh_lc, Wc16);
    conv_wl_kernel<<<512, 384, 0, stream>>>(Wih_cl, Whh_cl, Wl16);
    conv_bias_kernel<<<1, 512, 0, stream>>>(bih_lc, bhh_lc, bc, bih_cl, bhh_cl, bl);

    // ---- CSR build
    count_edges_kernel<<<(NEDGE + 255) / 256, 256, 0, stream>>>(lit_idx, counts);
    scan_kernel<<<1, 1024, 0, stream>>>(counts, starts, cursor);
    fill_csr_kernel<<<(NEDGE + 255) / 256, 256, 0, stream>>>(lit_idx, clause_idx,
                                                             cursor, edge_clause);

    // ---- message-passing iterations (h_l and h_c ping-pong in f16)
    const _Float16* hl_old[ITERS] = {h_l16_0, h_l16_1, h_l16_0, h_l16_1};
    _Float16*       hl_new[ITERS] = {h_l16_1, h_l16_0, h_l16_1, h_l16_0};
    const _Float16* hc_old[ITERS] = {h_c16_0, h_c16_1, h_c16_0, h_c16_1};
    _Float16*       hc_new[ITERS] = {h_c16_1, h_c16_0, h_c16_1, h_c16_0};

    for (int it = 0; it < ITERS; ++it) {
        clause_mfma_kernel<<<(NCLA / 64) * 2, 256, 0, stream>>>(
            hl_old[it], hc_old[it], hc_new[it], c_c, Wc16, bc, lit_idx);
        gather_msg_kernel<<<(NLIT * 16 + 255) / 256, 256, 0, stream>>>(
            hc_new[it], msg16, starts, edge_clause);
        literal_mfma_kernel<<<(NLIT / 64) * 2, 256, 0, stream>>>(
            hl_old[it], msg16, hl_new[it],
            (it == ITERS - 1) ? out_hl : (float*)nullptr,
            c_l, Wl16, bl, flip_perm);
    }

    votes_stage1_kernel<<<NLIT / 4, 256, 0, stream>>>(out_hl, out_w, out_b, out_votes);
    votes_stage2_kernel<<<BGR, 256, 0, stream>>>(out_votes, out);
}

// Round 4
// 533.436 us; speedup vs baseline: 7.8854x; 1.1543x over previous
//
#include <hip/hip_runtime.h>
#include <hip/hip_bf16.h>

// Problem constants (fixed by setup_inputs)
#define D     128
#define NLIT  32000
#define NCLA  64000
#define KLIT  3
#define NEDGE 192000
#define BGR   32
#define ITERS 4
#define LITS_PER_GRAPH 1000

typedef _Float16 f16x8 __attribute__((ext_vector_type(8)));
typedef float    f32x4 __attribute__((ext_vector_type(4)));

__device__ __forceinline__ float sigf(float x)  { return 1.f / (1.f + __expf(-x)); }
__device__ __forceinline__ float tanhft(float x){ return 1.f - 2.f / (__expf(2.f * x) + 1.f); }

// async 16B global -> LDS (wave-uniform LDS base, lane i lands at base + 16*i)
__device__ __forceinline__ void async_cp16(const void* g, void* l) {
    __builtin_amdgcn_global_load_lds((const __attribute__((address_space(1))) void*)g,
                                     (__attribute__((address_space(3))) void*)l,
                                     16, 0, 0);
}

// ---------------------------------------------------------------------------
// one-time conversions
// ---------------------------------------------------------------------------
__global__ void conv_x_kernel(const float* __restrict__ x, _Float16* __restrict__ o) {
    int t = blockIdx.x * blockDim.x + threadIdx.x;          // NLIT*16
    if (t >= NLIT * 16) return;
    const float* p = x + t * 8;
    f16x8 v;
#pragma unroll
    for (int i = 0; i < 8; ++i) v[i] = (_Float16)p[i];
    *(f16x8*)((_Float16*)o + t * 8) = v;
}

// Wc: 512 x 256 f16  ([n][k], k<128 from Wih, else Whh)
__global__ void conv_wc_kernel(const float* __restrict__ Wih,
                               const float* __restrict__ Whh,
                               _Float16* __restrict__ Wc) {
    int n = blockIdx.x, k = threadIdx.x;                    // 512 x 256
    float v = (k < 128) ? Wih[n * 128 + k] : Whh[n * 128 + k - 128];
    Wc[n * 256 + k] = (_Float16)v;
}

// Wl: 512 x 384 f16  ([n][k], k<256 from Wih, else Whh)
__global__ void conv_wl_kernel(const float* __restrict__ Wih,
                               const float* __restrict__ Whh,
                               _Float16* __restrict__ Wl) {
    int n = blockIdx.x, k = threadIdx.x;                    // 512 x 384
    float v = (k < 256) ? Wih[n * 256 + k] : Whh[n * 128 + k - 256];
    Wl[n * 384 + k] = (_Float16)v;
}

// bias combine + hc0 (= C_w + C_b as f16, the iter-0 h_c broadcast row)
__global__ void conv_bias_kernel(const float* bih_c, const float* bhh_c, float* bc,
                                 const float* bih_l, const float* bhh_l, float* bl,
                                 const float* C_w, const float* C_b,
                                 _Float16* hc0g) {
    int t = threadIdx.x;                                    // 512
    bc[t] = bih_c[t] + bhh_c[t];
    bl[t] = bih_l[t] + bhh_l[t];
    if (t < 128) hc0g[t] = (_Float16)(C_w[t] + C_b[t]);
}

// ---------------------------------------------------------------------------
// CSR build: counts -> (block sums -> scan -> block-local scan) -> fill
// ---------------------------------------------------------------------------
__global__ void count_edges_kernel(const int* __restrict__ lit_idx,
                                   int* __restrict__ counts) {
    int e = blockIdx.x * blockDim.x + threadIdx.x;
    if (e < NEDGE) atomicAdd(&counts[lit_idx[e]], 1);
}

// 125 blocks x 256: bsum[b] = sum of counts[b*256 .. b*256+255]
__global__ __launch_bounds__(256)
void block_sum_kernel(const int* __restrict__ counts, int* __restrict__ bsum) {
    int b = blockIdx.x, t = threadIdx.x;
    int v = counts[b * 256 + t];
    int lane = t & 63, w = t >> 6;
#pragma unroll
    for (int off = 32; off > 0; off >>= 1) v += __shfl_down(v, off, 64);
    __shared__ int ws[4];
    if (lane == 0) ws[w] = v;
    __syncthreads();
    if (t == 0) bsum[b] = ws[0] + ws[1] + ws[2] + ws[3];
}

// 1 block x 128: exclusive scan of 125 block sums; also starts[NLIT] = NEDGE
__global__ void scan_bsum_kernel(const int* __restrict__ bsum,
                                 int* __restrict__ ebsum,
                                 int* __restrict__ starts) {
    __shared__ int s[128];
    int t = threadIdx.x;
    int v = (t < 125) ? bsum[t] : 0;
    s[t] = v;
    __syncthreads();
    for (int off = 1; off < 128; off <<= 1) {
        int y = (t >= off) ? s[t - off] : 0;
        __syncthreads();
        s[t] += y;
        __syncthreads();
    }
    if (t < 125) ebsum[t] = s[t] - v;       // exclusive
    if (t == 0) starts[NLIT] = NEDGE;
}

// 125 blocks x 256: exclusive scan within block + global offset -> starts/cursor
__global__ __launch_bounds__(256)
void scan_write_kernel(const int* __restrict__ counts,
                       const int* __restrict__ ebsum,
                       int* __restrict__ starts,
                       int* __restrict__ cursor) {
    int b = blockIdx.x, t = threadIdx.x;
    int idx = b * 256 + t;
    int v = counts[idx];
    int lane = t & 63, w = t >> 6;
    int x = v;
#pragma unroll
    for (int off = 1; off < 64; off <<= 1) {
        int y = __shfl_up(x, off, 64);
        if (lane >= off) x += y;
    }
    __shared__ int wsum[4];
    if (lane == 63) wsum[w] = x;
    __syncthreads();
    int woff = 0;
#pragma unroll
    for (int i = 0; i < 4; ++i) if (i < w) woff += wsum[i];
    int g = ebsum[b] + woff + x - v;        // exclusive prefix
    starts[idx] = g;
    cursor[idx] = g;
}

__global__ void fill_csr_kernel(const int* __restrict__ lit_idx,
                                const int* __restrict__ clause_idx,
                                int* __restrict__ cursor,
                                int* __restrict__ edge_clause) {
    int e = blockIdx.x * blockDim.x + threadIdx.x;
    if (e < NEDGE) {
        int l = lit_idx[e];
        int pos = atomicAdd(&cursor[l], 1);
        edge_clause[pos] = clause_idx[e];
    }
}

// ---------------------------------------------------------------------------
// msg_l[l][:] = sum over clauses of literal l of h_c16[clause][:]   (f16 io, fp32 acc)
// ---------------------------------------------------------------------------
__global__ void gather_msg_kernel(const _Float16* __restrict__ h_c16,
                                  _Float16* __restrict__ msg16,
                                  const int* __restrict__ starts,
                                  const int* __restrict__ edge_clause) {
    int t = blockIdx.x * blockDim.x + threadIdx.x;          // NLIT*16
    if (t >= NLIT * 16) return;
    int l = t >> 4;
    int off = (t & 15) * 8;
    int s = starts[l], e = starts[l + 1];
    float a[8];
#pragma unroll
    for (int i = 0; i < 8; ++i) a[i] = 0.f;
    for (int j = s; j < e; ++j) {
        f16x8 v = *(const f16x8*)&h_c16[(size_t)edge_clause[j] * D + off];
#pragma unroll
        for (int i = 0; i < 8; ++i) a[i] += (float)v[i];
    }
    f16x8 o;
#pragma unroll
    for (int i = 0; i < 8; ++i) o[i] = (_Float16)a[i];
    *(f16x8*)&msg16[(size_t)l * D + off] = o;
}

// ---------------------------------------------------------------------------
// Clause LSTM (MFMA): 128 rows/block, d-half per block (c = bx&1).
// A = [gather3(h_l) | h_c_old], K=256. Wave w owns coltile u=w across all 8
// row-tiles and all 4 gates -> full LSTM quadruple in registers.
// ---------------------------------------------------------------------------
__global__ __launch_bounds__(256, 2)
void clause_mfma_kernel(const _Float16* __restrict__ h_l16,   // NLIT x 128
                        const _Float16* __restrict__ h_c_old, // NCLA x 128
                        _Float16* __restrict__ h_c_new,       // NCLA x 128
                        float* __restrict__ c_c,              // NCLA x 128
                        const _Float16* __restrict__ Wc,      // 512 x 256
                        const float* __restrict__ bc,         // 512
                        const _Float16* __restrict__ hc0g,    // 128 (iter-0 h_c row)
                        const int* __restrict__ lit_idx,
                        int first) {
    __shared__ _Float16 Wl[256 * 32];
    __shared__ _Float16 Al[128 * 32];
    __shared__ int      lidx[384];

    const int tid  = threadIdx.x;
    const int w    = tid >> 6;
    const int lane = tid & 63;
    const int qd   = lane >> 4;
    const int ln   = lane & 15;
    const int bx   = blockIdx.x;
    const int c    = bx & 1;             // d-half: cols [64c, 64c+64)
    const int row0 = (bx >> 1) * 128;

    for (int i = tid; i < 384; i += 256) lidx[i] = lit_idx[row0 * 3 + i];

    f32x4 acc[8][4];
#pragma unroll
    for (int R = 0; R < 8; ++R)
#pragma unroll
        for (int g = 0; g < 4; ++g) { acc[R][g][0]=0.f; acc[R][g][1]=0.f; acc[R][g][2]=0.f; acc[R][g][3]=0.f; }

    for (int ch = 0; ch < 8; ++ch) {
        const int k0 = ch * 32;
        __syncthreads();
        // ---- W stage: wave w stages gate-w rows (64 rows x 64B) via async
        {
            const int nbase = w * 128 + c * 64;
#pragma unroll
            for (int j = 0; j < 4; ++j) {
                int r = 16 * j + (lane >> 2);
                async_cp16(Wc + (nbase + r) * 256 + k0 + (lane & 3) * 8,
                           &Wl[(64 * w + 16 * j) * 32]);
            }
        }
        // ---- A stage (128 rows x 32 k)
        if (ch < 4) {
            // fused 3-literal gather: 512 slots, thread does 2
#pragma unroll
            for (int s2 = 0; s2 < 2; ++s2) {
                int s   = tid + 256 * s2;
                int m   = s >> 2;
                int off = (s & 3) * 8;
                int kk  = k0 + off;
                f16x8 v0 = *(const f16x8*)&h_l16[(size_t)lidx[3 * m + 0] * D + kk];
                f16x8 v1 = *(const f16x8*)&h_l16[(size_t)lidx[3 * m + 1] * D + kk];
                f16x8 v2 = *(const f16x8*)&h_l16[(size_t)lidx[3 * m + 2] * D + kk];
                f16x8 o;
#pragma unroll
                for (int i = 0; i < 8; ++i) o[i] = (_Float16)((float)v0[i] + (float)v1[i] + (float)v2[i]);
                *(f16x8*)&Al[m * 32 + off] = o;
            }
        } else if (first) {
            // iter 0: h_c row is the broadcast vector hc0g
#pragma unroll
            for (int s2 = 0; s2 < 2; ++s2) {
                int s   = tid + 256 * s2;
                int m   = s >> 2;
                int off = (s & 3) * 8;
                f16x8 v = *(const f16x8*)&hc0g[(k0 - 128) + off];
                *(f16x8*)&Al[m * 32 + off] = v;
            }
        } else {
            // copy own h_c rows: wave w stages rows 32w..32w+31 (two cps)
            int m = 32 * w + (lane >> 2);
            async_cp16(h_c_old + (size_t)(row0 + m) * D + (k0 - 128) + (lane & 3) * 8,
                       &Al[(32 * w) * 32]);
            async_cp16(h_c_old + (size_t)(row0 + m + 16) * D + (k0 - 128) + (lane & 3) * 8,
                       &Al[(32 * w + 16) * 32]);
        }
        __syncthreads();
        // ---- fragments + MFMA
        f16x8 af[8], bf[4];
#pragma unroll
        for (int R = 0; R < 8; ++R)
            af[R] = *(const f16x8*)&Al[(16 * R + ln) * 32 + qd * 8];
#pragma unroll
        for (int g = 0; g < 4; ++g)
            bf[g] = *(const f16x8*)&Wl[(64 * g + 16 * w + ln) * 32 + qd * 8];
#pragma unroll
        for (int R = 0; R < 8; ++R)
#pragma unroll
            for (int g = 0; g < 4; ++g)
                acc[R][g] = __builtin_amdgcn_mfma_f32_16x16x32_f16(af[R], bf[g], acc[R][g], 0, 0, 0);
    }

    // ---- fused LSTM epilogue (full i,f,g,o quadruple in registers)
    const int dcol = c * 64 + 16 * w + ln;     // 0..127
    const float b0 = bc[dcol], b1 = bc[128 + dcol], b2 = bc[256 + dcol], b3 = bc[384 + dcol];
#pragma unroll
    for (int R = 0; R < 8; ++R) {
#pragma unroll
        for (int r = 0; r < 4; ++r) {
            int m = row0 + 16 * R + qd * 4 + r;
            size_t idx = (size_t)m * D + dcol;
            float gi = acc[R][0][r] + b0;
            float gf = acc[R][1][r] + b1;
            float gg = acc[R][2][r] + b2;
            float go = acc[R][3][r] + b3;
            float cn = sigf(gi) * tanhft(gg);
            if (!first) cn += sigf(gf) * c_c[idx];
            float h  = sigf(go) * tanhft(cn);
            c_c[idx]     = cn;
            h_c_new[idx] = (_Float16)h;
        }
    }
}

// ---------------------------------------------------------------------------
// Literal LSTM (MFMA): A = [msg_l | h_old[flip] | h_old], K=384, 128 rows/block.
// All A staging is copy-type -> async global_load_lds.
// ---------------------------------------------------------------------------
__global__ __launch_bounds__(256, 2)
void literal_mfma_kernel(const _Float16* __restrict__ h_old16, // NLIT x 128
                         const _Float16* __restrict__ msg16,   // NLIT x 128
                         _Float16* __restrict__ h_new16,       // NLIT x 128
                         float* __restrict__ h32,              // optional fp32 out (final iter)
                         float* __restrict__ c_l,              // NLIT x 128
                         const _Float16* __restrict__ Wl384,   // 512 x 384
                         const float* __restrict__ bl,         // 512
                         const int* __restrict__ flip_perm,
                         int first) {
    __shared__ _Float16 Wl[256 * 32];
    __shared__ _Float16 Al[128 * 32];
    __shared__ int      flip_s[128];

    const int tid  = threadIdx.x;
    const int w    = tid >> 6;
    const int lane = tid & 63;
    const int qd   = lane >> 4;
    const int ln   = lane & 15;
    const int bx   = blockIdx.x;
    const int c    = bx & 1;
    const int row0 = (bx >> 1) * 128;

    if (tid < 128) flip_s[tid] = flip_perm[row0 + tid];

    f32x4 acc[8][4];
#pragma unroll
    for (int R = 0; R < 8; ++R)
#pragma unroll
        for (int g = 0; g < 4; ++g) { acc[R][g][0]=0.f; acc[R][g][1]=0.f; acc[R][g][2]=0.f; acc[R][g][3]=0.f; }

    for (int ch = 0; ch < 12; ++ch) {
        const int k0 = ch * 32;
        __syncthreads();
        // ---- W stage
        {
            const int nbase = w * 128 + c * 64;
#pragma unroll
            for (int j = 0; j < 4; ++j) {
                int r = 16 * j + (lane >> 2);
                async_cp16(Wl384 + (nbase + r) * 384 + k0 + (lane & 3) * 8,
                           &Wl[(64 * w + 16 * j) * 32]);
            }
        }
        // ---- A stage (all copies): wave w stages rows 32w..32w+31
        {
            int m0  = 32 * w + (lane >> 2);
            int sub = (lane & 3) * 8;
            const _Float16 *g0, *g1;
            if (ch < 4) {
                g0 = msg16 + (size_t)(row0 + m0) * D + k0 + sub;
                g1 = msg16 + (size_t)(row0 + m0 + 16) * D + k0 + sub;
            } else if (ch < 8) {
                g0 = h_old16 + (size_t)flip_s[m0] * D + (k0 - 128) + sub;
                g1 = h_old16 + (size_t)flip_s[m0 + 16] * D + (k0 - 128) + sub;
            } else {
                g0 = h_old16 + (size_t)(row0 + m0) * D + (k0 - 256) + sub;
                g1 = h_old16 + (size_t)(row0 + m0 + 16) * D + (k0 - 256) + sub;
            }
            async_cp16(g0, &Al[(32 * w) * 32]);
            async_cp16(g1, &Al[(32 * w + 16) * 32]);
        }
        __syncthreads();
        // ---- fragments + MFMA
        f16x8 af[8], bf[4];
#pragma unroll
        for (int R = 0; R < 8; ++R)
            af[R] = *(const f16x8*)&Al[(16 * R + ln) * 32 + qd * 8];
#pragma unroll
        for (int g = 0; g < 4; ++g)
            bf[g] = *(const f16x8*)&Wl[(64 * g + 16 * w + ln) * 32 + qd * 8];
#pragma unroll
        for (int R = 0; R < 8; ++R)
#pragma unroll
            for (int g = 0; g < 4; ++g)
                acc[R][g] = __builtin_amdgcn_mfma_f32_16x16x32_f16(af[R], bf[g], acc[R][g], 0, 0, 0);
    }

    const int dcol = c * 64 + 16 * w + ln;
    const float b0 = bl[dcol], b1 = bl[128 + dcol], b2 = bl[256 + dcol], b3 = bl[384 + dcol];
#pragma unroll
    for (int R = 0; R < 8; ++R) {
#pragma unroll
        for (int r = 0; r < 4; ++r) {
            int m = row0 + 16 * R + qd * 4 + r;
            size_t idx = (size_t)m * D + dcol;
            float gi = acc[R][0][r] + b0;
            float gf = acc[R][1][r] + b1;
            float gg = acc[R][2][r] + b2;
            float go = acc[R][3][r] + b3;
            float cn = sigf(gi) * tanhft(gg);
            if (!first) cn += sigf(gf) * c_l[idx];
            float h  = sigf(go) * tanhft(cn);
            c_l[idx]     = cn;
            h_new16[idx] = (_Float16)h;
            if (h32) h32[idx] = h;
        }
    }
}

// ---------------------------------------------------------------------------
// votes stage 1: one wave per literal, no atomics.
// ---------------------------------------------------------------------------
__global__ __launch_bounds__(256)
void votes_stage1_kernel(const float* __restrict__ h_l,
                         const float* __restrict__ out_w,
                         const float* __restrict__ out_b,
                         float* __restrict__ votes_out) {
    int w    = threadIdx.x >> 6;            // wave in block
    int lane = threadIdx.x & 63;
    int l    = blockIdx.x * 4 + w;          // grid = NLIT/4
    if (l >= NLIT) return;
    const float2 v = *(const float2*)&h_l[(size_t)l * D + lane * 2];
    const float2 ww = *(const float2*)&out_w[lane * 2];
    float p = v.x * ww.x + v.y * ww.y;
#pragma unroll
    for (int off = 32; off > 0; off >>= 1) p += __shfl_down(p, off, 64);
    if (lane == 0) votes_out[l] = p + out_b[0];
}

// votes stage 2: one block per graph, sum 1000 contiguous votes -> mean
__global__ __launch_bounds__(256)
void votes_stage2_kernel(const float* __restrict__ votes,
                         float* __restrict__ out0) {
    int b = blockIdx.x;                     // 32 graphs
    int t = threadIdx.x;
    const float* base = votes + (size_t)b * LITS_PER_GRAPH;
    float s = 0.f;
    for (int i = t; i < LITS_PER_GRAPH; i += 256) s += base[i];
#pragma unroll
    for (int off = 32; off > 0; off >>= 1) s += __shfl_down(s, off, 64);
    __shared__ float ws[4];
    if ((t & 63) == 0) ws[t >> 6] = s;
    __syncthreads();
    if (t == 0) out0[b] = (ws[0] + ws[1] + ws[2] + ws[3]) / (float)LITS_PER_GRAPH;
}

// ---------------------------------------------------------------------------
extern "C" void kernel_launch(void* const* d_in, const int* in_sizes, int n_in,
                              void* d_out, int out_size, void* d_ws, size_t ws_size,
                              hipStream_t stream) {
    (void)in_sizes; (void)n_in; (void)out_size; (void)ws_size;

    const float* x_unk  = (const float*)d_in[0];
    const float* C_w    = (const float*)d_in[1];
    const float* C_b    = (const float*)d_in[2];
    const float* Wih_lc = (const float*)d_in[3];
    const float* Whh_lc = (const float*)d_in[4];
    const float* bih_lc = (const float*)d_in[5];
    const float* bhh_lc = (const float*)d_in[6];
    const float* Wih_cl = (const float*)d_in[7];
    const float* Whh_cl = (const float*)d_in[8];
    const float* bih_cl = (const float*)d_in[9];
    const float* bhh_cl = (const float*)d_in[10];
    const float* out_w  = (const float*)d_in[11];
    const float* out_b  = (const float*)d_in[12];
    const int* lit_idx    = (const int*)d_in[13];
    const int* clause_idx = (const int*)d_in[14];
    const int* flip_perm  = (const int*)d_in[16];

    // ---- workspace layout (bytes, 256-aligned chunks)
    char* W = (char*)d_ws;
    size_t off = 0;
    auto alloc = [&](size_t bytes) { char* p = W + off; off = (off + bytes + 255) & ~(size_t)255; return p; };
    _Float16* h_l16_0 = (_Float16*)alloc((size_t)NLIT * D * 2);
    _Float16* h_l16_1 = (_Float16*)alloc((size_t)NLIT * D * 2);
    _Float16* h_c16_0 = (_Float16*)alloc((size_t)NCLA * D * 2);
    _Float16* h_c16_1 = (_Float16*)alloc((size_t)NCLA * D * 2);
    _Float16* msg16   = (_Float16*)alloc((size_t)NLIT * D * 2);
    float*    c_l     = (float*)  alloc((size_t)NLIT * D * 4);
    float*    c_c     = (float*)  alloc((size_t)NCLA * D * 4);
    _Float16* Wc16    = (_Float16*)alloc(512 * 256 * 2);
    _Float16* Wl16    = (_Float16*)alloc(512 * 384 * 2);
    float*    bc      = (float*)  alloc(512 * 4);
    float*    bl      = (float*)  alloc(512 * 4);
    _Float16* hc0g    = (_Float16*)alloc(128 * 2);
    int* counts       = (int*)alloc((size_t)NLIT * 4);
    int* starts       = (int*)alloc((size_t)(NLIT + 1) * 4);
    int* cursor       = (int*)alloc((size_t)NLIT * 4);
    int* edge_clause  = (int*)alloc((size_t)NEDGE * 4);
    int* bsum         = (int*)alloc(128 * 4);
    int* ebsum        = (int*)alloc(128 * 4);

    float* out       = (float*)d_out;
    float* out_votes = out + BGR;
    float* out_hl    = out + BGR + NLIT;

    // counts must start at zero for the atomic histogram
    hipMemsetAsync(counts, 0, (size_t)NLIT * 4, stream);

    // ---- one-time conversions
    conv_x_kernel<<<(NLIT * 16 + 255) / 256, 256, 0, stream>>>(x_unk, h_l16_0);
    conv_wc_kernel<<<512, 256, 0, stream>>>(Wih_lc, Whh_lc, Wc16);
    conv_wl_kernel<<<512, 384, 0, stream>>>(Wih_cl, Whh_cl, Wl16);
    conv_bias_kernel<<<1, 512, 0, stream>>>(bih_lc, bhh_lc, bc, bih_cl, bhh_cl, bl,
                                            C_w, C_b, hc0g);

    // ---- CSR build (parallel scan)
    count_edges_kernel<<<(NEDGE + 255) / 256, 256, 0, stream>>>(lit_idx, counts);
    block_sum_kernel<<<NLIT / 256, 256, 0, stream>>>(counts, bsum);
    scan_bsum_kernel<<<1, 128, 0, stream>>>(bsum, ebsum, starts);
    scan_write_kernel<<<NLIT / 256, 256, 0, stream>>>(counts, ebsum, starts, cursor);
    fill_csr_kernel<<<(NEDGE + 255) / 256, 256, 0, stream>>>(lit_idx, clause_idx,
                                                             cursor, edge_clause);

    // ---- message-passing iterations (h_l and h_c ping-pong in f16)
    const _Float16* hl_old[ITERS] = {h_l16_0, h_l16_1, h_l16_0, h_l16_1};
    _Float16*       hl_new[ITERS] = {h_l16_1, h_l16_0, h_l16_1, h_l16_0};
    const _Float16* hc_old[ITERS] = {h_c16_0, h_c16_1, h_c16_0, h_c16_1};
    _Float16*       hc_new[ITERS] = {h_c16_1, h_c16_0, h_c16_1, h_c16_0};

    for (int it = 0; it < ITERS; ++it) {
        clause_mfma_kernel<<<(NCLA / 128) * 2, 256, 0, stream>>>(
            hl_old[it], hc_old[it], hc_new[it], c_c, Wc16, bc, hc0g, lit_idx,
            it == 0 ? 1 : 0);
        gather_msg_kernel<<<(NLIT * 16 + 255) / 256, 256, 0, stream>>>(
            hc_new[it], msg16, starts, edge_clause);
        literal_mfma_kernel<<<(NLIT / 128) * 2, 256, 0, stream>>>(
            hl_old[it], msg16, hl_new[it],
            (it == ITERS - 1) ? out_hl : (float*)nullptr,
            c_l, Wl16, bl, flip_perm,
            it == 0 ? 1 : 0);
    }

    votes_stage1_kernel<<<NLIT / 4, 256, 0, stream>>>(out_hl, out_w, out_b, out_votes);
    votes_stage2_kernel<<<BGR, 256, 0, stream>>>(out_votes, out);
}